// Round 1
// 333.135 us; speedup vs baseline: 1.1501x; 1.1501x over previous
//
#include <hip/hip_runtime.h>
#include <hip/hip_bf16.h>
#include <stdint.h>

typedef __hip_bfloat16 bf16;
typedef __attribute__((ext_vector_type(4))) float f32x4;
typedef __attribute__((ext_vector_type(8))) short short8;

#define SEQ   4096
#define CDIM  1024

// ---------------------------------------------------------------------------
// async global->LDS, 16B per lane. LDS dest = wave-uniform base + lane*16.
// ---------------------------------------------------------------------------
__device__ __forceinline__ void async_load16(const void* g, void* l) {
  auto gp = reinterpret_cast<const __attribute__((address_space(1))) uint32_t*>(
      reinterpret_cast<uintptr_t>(g));
  auto lp = reinterpret_cast<__attribute__((address_space(3))) uint32_t*>(
      static_cast<uint32_t>(reinterpret_cast<uintptr_t>(l)));
  __builtin_amdgcn_global_load_lds(gp, lp, 16, 0, 0);
}

// ---------------------------------------------------------------------------
// fused fp32 -> bf16 convert for x, w_qkv, w_proj (one launch)
// ---------------------------------------------------------------------------
__global__ __launch_bounds__(256) void convert3_kernel(const float* __restrict__ x,
                                                       const float* __restrict__ wq,
                                                       const float* __restrict__ wp,
                                                       bf16* __restrict__ xb,
                                                       bf16* __restrict__ wqb,
                                                       bf16* __restrict__ wpb) {
  int i = blockIdx.x * 256 + threadIdx.x;
  const float* src;
  bf16* dst;
  int off;
  if (i < 4194304)      { src = x;  dst = xb;  off = i; }
  else if (i < 4980736) { src = wq; dst = wqb; off = i - 4194304; }
  else                  { src = wp; dst = wpb; off = i - 4980736; }
  float4 f = ((const float4*)src)[off];
  union { bf16 b[4]; ushort4 u; } c;
  c.b[0] = __float2bfloat16(f.x);
  c.b[1] = __float2bfloat16(f.y);
  c.b[2] = __float2bfloat16(f.z);
  c.b[3] = __float2bfloat16(f.w);
  ((ushort4*)dst)[off] = c.u;
}

// ---------------------------------------------------------------------------
// 256x256 8-phase bf16 GEMM (T2 swizzle + T3/T4 counted vmcnt + T5 setprio).
//   C[m][n] = sum_k A[m][k] * B[n][k]   (both row-major, K-contiguous)
// 512 threads = 8 waves (2M x 4N); per-wave output 128x64; BK=64.
// LDS: A0,B0,A1,B1 each [256][64] bf16 = 4 x 32 KiB = 128 KiB (dbuf by K-tile
// parity). st_16x32 swizzle: LDS stays linear for global_load_lds; the global
// SOURCE column is pre-swizzled per-lane (col ^= 16 iff lane>=32, i.e. row&4),
// and ds_reads apply the same XOR (col ^= (lr&4)<<2).
// Staging stream: the half-tile staged in phase p is the region last read in
// phase p-1 -> vmcnt(6) at phases 4 and 8 is sufficient (3 half-tiles in
// flight are always the 3 not yet needed).
// ---------------------------------------------------------------------------
#define BARR()  __builtin_amdgcn_s_barrier()
#define LGKM0() asm volatile("s_waitcnt lgkmcnt(0)" ::: "memory")
#define VMW6()  asm volatile("s_waitcnt vmcnt(6)" ::: "memory")
#define VMW0()  asm volatile("s_waitcnt vmcnt(0)" ::: "memory")
#define SP(x)   __builtin_amdgcn_s_setprio(x)

// A half h: rows {h*64 + [0,64)} u {h*64+128 + [0,64)}; wave w stages 8 rows.
#define STA(buf, kc, h)                                                        \
  {                                                                            \
    const int ra_ = (h) * 64 + w * 8;                                          \
    async_load16(Ag + (size_t)(ra_ + lr8) * K + (kc) + cs, (buf) + ra_ * 64);  \
    async_load16(Ag + (size_t)(ra_ + 128 + lr8) * K + (kc) + cs,               \
                 (buf) + (ra_ + 128) * 64);                                    \
  }
// B half h: rows {wn'*64 + h*32 + [0,32) : wn'=0..3}; wave w stages 8 rows.
#define STB(buf, kc, h)                                                        \
  {                                                                            \
    const int rb_ = (w & 3) * 8 + (w >> 2) * 64 + (h) * 32;                    \
    async_load16(Bg + (size_t)(rb_ + lr8) * K + (kc) + cs, (buf) + rb_ * 64);  \
    async_load16(Bg + (size_t)(rb_ + 128 + lr8) * K + (kc) + cs,               \
                 (buf) + (rb_ + 128) * 64);                                    \
  }

#define RD_A(buf, h)                                                           \
  {                                                                            \
    _Pragma("unroll") for (int mi = 0; mi < 4; ++mi) {                         \
      const unsigned short* p_ = (buf) + (arow0 + (h) * 64 + mi * 16) * 64;    \
      af[mi][0] = *(const short8*)(p_ + ((lq * 8) ^ sw));                      \
      af[mi][1] = *(const short8*)(p_ + ((32 + lq * 8) ^ sw));                 \
    }                                                                          \
  }
#define RD_B(buf, h)                                                           \
  {                                                                            \
    _Pragma("unroll") for (int ni = 0; ni < 2; ++ni) {                         \
      const unsigned short* p_ = (buf) + (brow0 + (h) * 32 + ni * 16) * 64;    \
      bfr[ni][0] = *(const short8*)(p_ + ((lq * 8) ^ sw));                     \
      bfr[ni][1] = *(const short8*)(p_ + ((32 + lq * 8) ^ sw));                \
    }                                                                          \
  }

#define MMA(MQ, NQ)                                                            \
  {                                                                            \
    _Pragma("unroll") for (int ks = 0; ks < 2; ++ks)                           \
      _Pragma("unroll") for (int mi = 0; mi < 4; ++mi)                         \
        _Pragma("unroll") for (int ni = 0; ni < 2; ++ni)                       \
          acc[(MQ) * 4 + mi][(NQ) * 2 + ni] =                                  \
              __builtin_amdgcn_mfma_f32_16x16x32_bf16(                         \
                  af[mi][ks], bfr[ni][ks], acc[(MQ) * 4 + mi][(NQ) * 2 + ni],  \
                  0, 0, 0);                                                    \
  }

// one full iteration: compute tiles (kc)/buf0 [ph1-4] and (kc+64)/buf1 [ph5-8]
// while staging tiles kc+128 (buf0) and kc+192 (buf1) + Bh0(buf1,kc+64) at ph1.
#define FULL_ITER(kc)                                                          \
  RD_A(A0, 0); RD_B(B0, 0); STB(B1, (kc) + 64, 0);                             \
  BARR(); LGKM0(); SP(1); MMA(0, 0); SP(0); BARR();                            \
  RD_B(B0, 1); STA(A0, (kc) + 128, 0);                                         \
  BARR(); LGKM0(); SP(1); MMA(0, 1); SP(0); BARR();                            \
  RD_A(A0, 1); STB(B0, (kc) + 128, 1);                                         \
  BARR(); LGKM0(); SP(1); MMA(1, 1); SP(0); BARR();                            \
  RD_B(B0, 0); STA(A0, (kc) + 128, 1); VMW6();                                 \
  BARR(); LGKM0(); SP(1); MMA(1, 0); SP(0); BARR();                            \
  RD_A(A1, 0); RD_B(B1, 0); STB(B0, (kc) + 128, 0);                            \
  BARR(); LGKM0(); SP(1); MMA(0, 0); SP(0); BARR();                            \
  RD_B(B1, 1); STA(A1, (kc) + 192, 0);                                         \
  BARR(); LGKM0(); SP(1); MMA(0, 1); SP(0); BARR();                            \
  RD_A(A1, 1); STB(B1, (kc) + 192, 1);                                         \
  BARR(); LGKM0(); SP(1); MMA(1, 1); SP(0); BARR();                            \
  RD_B(B1, 0); STA(A1, (kc) + 192, 1); VMW6();                                 \
  BARR(); LGKM0(); SP(1); MMA(1, 0); SP(0); BARR();

// last iteration: only Bh0(buf1) still needs staging; drain with vmcnt(0).
#define FINAL_ITER(kc)                                                         \
  RD_A(A0, 0); RD_B(B0, 0); STB(B1, (kc) + 64, 0);                             \
  BARR(); LGKM0(); SP(1); MMA(0, 0); SP(0); BARR();                            \
  RD_B(B0, 1);                                                                 \
  BARR(); LGKM0(); SP(1); MMA(0, 1); SP(0); BARR();                            \
  RD_A(A0, 1);                                                                 \
  BARR(); LGKM0(); SP(1); MMA(1, 1); SP(0); BARR();                            \
  RD_B(B0, 0); VMW0();                                                         \
  BARR(); LGKM0(); SP(1); MMA(1, 0); SP(0); BARR();                            \
  RD_A(A1, 0); RD_B(B1, 0);                                                    \
  BARR(); LGKM0(); SP(1); MMA(0, 0); SP(0); BARR();                            \
  RD_B(B1, 1);                                                                 \
  BARR(); LGKM0(); SP(1); MMA(0, 1); SP(0); BARR();                            \
  RD_A(A1, 1);                                                                 \
  BARR(); LGKM0(); SP(1); MMA(1, 1); SP(0); BARR();                            \
  RD_B(B1, 0);                                                                 \
  LGKM0(); SP(1); MMA(1, 0); SP(0);

template <int EPI>
__global__ __launch_bounds__(512, 2) void gemm256(const bf16* __restrict__ X,
                                                  const bf16* __restrict__ W,
                                                  const float* __restrict__ bias,
                                                  bf16* __restrict__ Qo,
                                                  bf16* __restrict__ Ko,
                                                  bf16* __restrict__ Vo,
                                                  float* __restrict__ Out,
                                                  const int K) {
  __shared__ __attribute__((aligned(16))) unsigned short lds[4][256 * 64];
  unsigned short* const A0 = lds[0];
  unsigned short* const B0 = lds[1];
  unsigned short* const A1 = lds[2];
  unsigned short* const B1 = lds[3];

  const int tid  = threadIdx.x;
  const int w    = tid >> 6, lane = tid & 63;
  const int wm   = w >> 2,   wn   = w & 3;
  const int lr   = lane & 15, lq  = lane >> 4;
  const int bm   = blockIdx.y, bn = blockIdx.x;
  const int sw   = (lr & 4) << 2;                                 // read-side XOR (elems)
  const int cs   = ((lane & 7) << 3) ^ (((lane >> 5) & 1) << 4);  // src-side pre-swizzle
  const int lr8  = lane >> 3;

  const bool swapped = (EPI == 0) && (bn < 4);
  const bf16* Xg = X + (size_t)(bm * 256) * K;
  const bf16* Wg = W + (size_t)(bn * 256) * K;
  const bf16* Ag = swapped ? Wg : Xg;
  const bf16* Bg = swapped ? Xg : Wg;

  const int arow0 = wm * 128 + lr;
  const int brow0 = wn * 64 + lr;

  short8 af[4][2], bfr[2][2];
  f32x4 acc[8][4] = {};

  // prologue: buf0 tile0 fully; buf1 tile1 {Ah0,Bh1,Ah1} (Bh0(b1) comes at ph1)
  STA(A0, 0, 0);
  STB(B0, 0, 0);
  STB(B0, 0, 1);
  STA(A0, 0, 1);
  STA(A1, 64, 0);
  STB(B1, 64, 1);
  STA(A1, 64, 1);
  VMW6();            // first 4 half-tiles (all of buf0) landed
  BARR();

#pragma unroll 1
  for (int kc = 0; kc < K - 128; kc += 128) {
    FULL_ITER(kc);
  }
  FINAL_ITER(K - 128);

  // ------------------------- epilogue -------------------------
  if constexpr (EPI == 0) {
    if (swapped) {
      // Q block: m = channel j, col = token t. 4 regs = 4 consecutive d.
#pragma unroll
      for (int mt = 0; mt < 8; ++mt) {
        const int j0 = bn * 256 + wm * 128 + mt * 16 + lq * 4;
        const int h  = j0 >> 6, d0 = j0 & 63;
#pragma unroll
        for (int nt = 0; nt < 4; ++nt) {
          const int t = bm * 256 + wn * 64 + nt * 16 + lr;
          const int b = t >> 12, n = t & 4095;
          union { bf16 v[4]; ushort4 u; } pk;
#pragma unroll
          for (int r = 0; r < 4; ++r) {
            float v = acc[mt][nt][r];
            v = (v > 0.0f) ? (v + 1.0f) : __expf(v);
            pk.v[r] = __float2bfloat16(v);
          }
          *(ushort4*)(Qo + (((size_t)((b * 16 + h) * SEQ + n)) << 6) + d0) = pk.u;
        }
      }
    } else {
      // K/V block: m = token t, col = channel j. 4 regs = 4 consecutive n.
#pragma unroll
      for (int nt = 0; nt < 4; ++nt) {
        const int j   = bn * 256 + wn * 64 + nt * 16 + lr;
        const int sel = j >> 10;           // 1 = K, 2 = V
        const int h   = (j >> 6) & 15;
        const int d   = j & 63;
        bf16* dst = (sel == 1) ? Ko : Vo;
#pragma unroll
        for (int mt = 0; mt < 8; ++mt) {
          const int t0 = bm * 256 + wm * 128 + mt * 16 + lq * 4;
          const int b = t0 >> 12, n0 = t0 & 4095;
          union { bf16 v[4]; ushort4 u; } pk;
#pragma unroll
          for (int r = 0; r < 4; ++r) {
            float v = acc[mt][nt][r];
            if (sel == 1) v = (v > 0.0f) ? (v + 1.0f) : __expf(v);
            pk.v[r] = __float2bfloat16(v);
          }
          *(ushort4*)(dst + ((size_t)((b * 16 + h) * 64 + d)) * SEQ + n0) = pk.u;
        }
      }
    }
  } else {
    // proj: m = token t, col = channel. Coalesced scalar fp32 stores + bias.
#pragma unroll
    for (int mt = 0; mt < 8; ++mt) {
#pragma unroll
      for (int r = 0; r < 4; ++r) {
        const int t = bm * 256 + wm * 128 + mt * 16 + lq * 4 + r;
        float* op = Out + (size_t)t * CDIM + bn * 256 + wn * 64 + lr;
#pragma unroll
        for (int nt = 0; nt < 4; ++nt)
          op[nt * 16] = acc[mt][nt][r] + bias[bn * 256 + wn * 64 + nt * 16 + lr];
      }
    }
  }
}

// ---------------------------------------------------------------------------
// kv partials via MFMA.  Inputs K^T,V^T [bh][d][n] (n contiguous).
// ---------------------------------------------------------------------------
__global__ __launch_bounds__(256) void kv_mfma(const bf16* __restrict__ KT,
                                               const bf16* __restrict__ VT,
                                               float* __restrict__ KVp,
                                               float* __restrict__ KSp) {
  __shared__ bf16 kt[64 * 64];
  __shared__ bf16 vt[64 * 64];
  const int tid = threadIdx.x;
  const int w = tid >> 6, lane = tid & 63;
  const int wm = w >> 1, wn = w & 1;
  const int lr = lane & 15, lq = lane >> 4;
  const int sp = blockIdx.x, bh = blockIdx.y;
  const bf16* kg0 = KT + (size_t)bh * 64 * SEQ + sp * 512;
  const bf16* vg0 = VT + (size_t)bh * 64 * SEQ + sp * 512;

  f32x4 acc[2][2] = {};
  f32x4 kacc0 = {}, kacc1 = {};
  short8 ones;
#pragma unroll
  for (int j = 0; j < 8; ++j) ((unsigned short*)&ones)[j] = 0x3F80;  // bf16 1.0

  for (int nc = 0; nc < 8; ++nc) {
    __syncthreads();
#pragma unroll
    for (int i = 0; i < 2; ++i) {
      const int row = w * 16 + i * 8 + (lane >> 3);
      const int col = (lane & 7) * 8;
      async_load16(kg0 + (size_t)row * SEQ + nc * 64 + col, kt + (w * 16 + i * 8) * 64);
      async_load16(vg0 + (size_t)row * SEQ + nc * 64 + col, vt + (w * 16 + i * 8) * 64);
    }
    __syncthreads();

#pragma unroll
    for (int ks = 0; ks < 2; ++ks) {
      short8 a0 = *(const short8*)&kt[(wm * 32 +      lr) * 64 + ks * 32 + lq * 8];
      short8 a1 = *(const short8*)&kt[(wm * 32 + 16 + lr) * 64 + ks * 32 + lq * 8];
      short8 b0 = *(const short8*)&vt[(wn * 32 +      lr) * 64 + ks * 32 + lq * 8];
      short8 b1 = *(const short8*)&vt[(wn * 32 + 16 + lr) * 64 + ks * 32 + lq * 8];
      acc[0][0] = __builtin_amdgcn_mfma_f32_16x16x32_bf16(a0, b0, acc[0][0], 0, 0, 0);
      acc[0][1] = __builtin_amdgcn_mfma_f32_16x16x32_bf16(a0, b1, acc[0][1], 0, 0, 0);
      acc[1][0] = __builtin_amdgcn_mfma_f32_16x16x32_bf16(a1, b0, acc[1][0], 0, 0, 0);
      acc[1][1] = __builtin_amdgcn_mfma_f32_16x16x32_bf16(a1, b1, acc[1][1], 0, 0, 0);
      kacc0 = __builtin_amdgcn_mfma_f32_16x16x32_bf16(a0, ones, kacc0, 0, 0, 0);
      kacc1 = __builtin_amdgcn_mfma_f32_16x16x32_bf16(a1, ones, kacc1, 0, 0, 0);
    }
  }

  float* outp = KVp + ((size_t)(sp * 64 + bh)) * 4096;
#pragma unroll
  for (int mt = 0; mt < 2; ++mt)
#pragma unroll
    for (int nt = 0; nt < 2; ++nt) {
      const int e  = wn * 32 + nt * 16 + lr;
      const int d0 = wm * 32 + mt * 16 + lq * 4;
      *(float4*)&outp[e * 64 + d0] = *(float4*)&acc[mt][nt];
    }
  if (wn == 0 && lr == 0) {
    float* ksp = KSp + (size_t)(sp * 64 + bh) * 64 + wm * 32;
#pragma unroll
    for (int r = 0; r < 4; ++r) {
      ksp[lq * 4 + r]      = kacc0[r];
      ksp[16 + lq * 4 + r] = kacc1[r];
    }
  }
}

// ---------------------------------------------------------------------------
__global__ __launch_bounds__(256) void kv_reduce(const float* __restrict__ KVp,
                                                 const float* __restrict__ KSp,
                                                 bf16* __restrict__ KVT,
                                                 float* __restrict__ KS) {
  const int bh = blockIdx.x, t = threadIdx.x;
#pragma unroll 4
  for (int i = 0; i < 16; ++i) {
    const int idx = i * 256 + t;
    float s = 0.0f;
#pragma unroll
    for (int sp = 0; sp < 8; ++sp) s += KVp[((size_t)(sp * 64 + bh)) * 4096 + idx];
    const bf16 hi = __float2bfloat16(s);
    const float lo = s - __bfloat162float(hi);
    const int e = idx >> 6, d = idx & 63;
    KVT[(size_t)bh * 8192 + e * 128 + d]      = hi;
    KVT[(size_t)bh * 8192 + e * 128 + 64 + d] = __float2bfloat16(lo);
  }
  if (t < 64) {
    float s = 0.0f;
#pragma unroll
    for (int sp = 0; sp < 8; ++sp) s += KSp[(sp * 64 + bh) * 64 + t];
    KS[bh * 64 + t] = s;
  }
}

// ---------------------------------------------------------------------------
__global__ __launch_bounds__(256) void num_mfma(const bf16* __restrict__ Qb,
                                                const bf16* __restrict__ KVT,
                                                const float* __restrict__ KS,
                                                bf16* __restrict__ Attn) {
  __shared__ bf16 qs[128 * 64];
  __shared__ bf16 kvs[64 * 128];
  __shared__ bf16 Cs[128 * 72];
  __shared__ float ksl[64];
  __shared__ float dred[256];
  __shared__ float den[128];
  const int tid = threadIdx.x;
  const int w = tid >> 6, lane = tid & 63;
  const int wm = w >> 1, wn = w & 1;
  const int lr = lane & 15, lq = lane >> 4;
  const int bh = blockIdx.y, n00 = blockIdx.x * 128;
  const int b = bh >> 4, h = bh & 15;

  const bf16* qg  = Qb  + ((size_t)bh * SEQ + n00) * 64;
  const bf16* kvg = KVT + (size_t)bh * 8192;
#pragma unroll
  for (int i = 0; i < 4; ++i) {
    const int row = w * 32 + i * 8 + (lane >> 3);
    async_load16(qg + (size_t)row * 64 + (lane & 7) * 8, qs + (w * 32 + i * 8) * 64);
  }
#pragma unroll
  for (int i = 0; i < 4; ++i) {
    const int row = w * 16 + i * 4 + (lane >> 4);
    async_load16(kvg + (size_t)row * 128 + (lane & 15) * 8, kvs + (w * 16 + i * 4) * 128);
  }
  if (tid < 64) ksl[tid] = KS[bh * 64 + tid];
  __syncthreads();

  {
    const int n = tid >> 1, half = tid & 1;
    float s = 0.0f;
#pragma unroll
    for (int v8 = 0; v8 < 4; ++v8) {
      short8 qq = *(const short8*)&qs[n * 64 + half * 32 + v8 * 8];
#pragma unroll
      for (int j = 0; j < 8; ++j)
        s += __bfloat162float(((const bf16*)&qq)[j]) * ksl[half * 32 + v8 * 8 + j];
    }
    dred[tid] = s;
  }

  short8 afr[4][2], bfr2[2][4];
#pragma unroll
  for (int mt = 0; mt < 4; ++mt)
#pragma unroll
    for (int kh = 0; kh < 2; ++kh)
      afr[mt][kh] = *(const short8*)&qs[(wm * 64 + mt * 16 + lr) * 64 + kh * 32 + lq * 8];
#pragma unroll
  for (int nt = 0; nt < 2; ++nt)
#pragma unroll
    for (int ks = 0; ks < 4; ++ks)
      bfr2[nt][ks] = *(const short8*)&kvs[(wn * 32 + nt * 16 + lr) * 128 + ks * 32 + lq * 8];

  f32x4 acc[4][2] = {};
#pragma unroll
  for (int ks = 0; ks < 4; ++ks)
#pragma unroll
    for (int mt = 0; mt < 4; ++mt)
#pragma unroll
      for (int nt = 0; nt < 2; ++nt)
        acc[mt][nt] = __builtin_amdgcn_mfma_f32_16x16x32_bf16(afr[mt][ks & 1], bfr2[nt][ks],
                                                              acc[mt][nt], 0, 0, 0);
  __syncthreads();
  if (tid < 128) den[tid] = dred[tid * 2] + dred[tid * 2 + 1] + 1e-8f;
  __syncthreads();

#pragma unroll
  for (int mt = 0; mt < 4; ++mt) {
#pragma unroll
    for (int r = 0; r < 4; ++r) {
      const int nl = wm * 64 + mt * 16 + lq * 4 + r;
      const float inv = 1.0f / den[nl];
#pragma unroll
      for (int nt = 0; nt < 2; ++nt) {
        const int e = wn * 32 + nt * 16 + lr;
        Cs[nl * 72 + e] = __float2bfloat16(acc[mt][nt][r] * inv);
      }
    }
  }
  __syncthreads();
#pragma unroll
  for (int it = 0; it < 4; ++it) {
    const int nl = it * 32 + (tid >> 3);
    const int ch = tid & 7;
    short8 val = *(const short8*)&Cs[nl * 72 + ch * 8];
    *(short8*)(Attn + ((size_t)(b * SEQ + n00 + nl)) * CDIM + h * 64 + ch * 8) = val;
  }
}

// ---------------------------------------------------------------------------
extern "C" void kernel_launch(void* const* d_in, const int* in_sizes, int n_in,
                              void* d_out, int out_size, void* d_ws, size_t ws_size,
                              hipStream_t stream) {
  const float* x      = (const float*)d_in[0];
  const float* w_qkv  = (const float*)d_in[1];
  const float* w_proj = (const float*)d_in[2];
  const float* b_proj = (const float*)d_in[3];
  float* out = (float*)d_out;
  char* ws = (char*)d_ws;

  bf16*  xb     = (bf16*)(ws + 0);
  bf16*  wqkvb  = (bf16*)(ws + 33554432);
  bf16*  wprojb = (bf16*)(ws + 39845888);
  bf16*  qb     = (bf16*)(ws + 41943040);
  bf16*  ktb    = (bf16*)(ws + 75497472);
  bf16*  vtb    = (bf16*)(ws + 109051904);
  float* kvp    = (float*)(ws + 0);
  float* ksp    = (float*)(ws + 8388608);
  bf16*  kvt    = (bf16*)(ws + 142606336);
  float* ksum   = (float*)(ws + 143654912);
  bf16*  attn   = (bf16*)(ws + 0);

  convert3_kernel<<<20480, 256, 0, stream>>>(x, w_qkv, w_proj, xb, wqkvb, wprojb);

  gemm256<0><<<dim3(12, 64), 512, 0, stream>>>(xb, wqkvb, nullptr, qb, ktb, vtb, nullptr, 1024);
  kv_mfma<<<dim3(8, 64), 256, 0, stream>>>(ktb, vtb, kvp, ksp);
  kv_reduce<<<64, 256, 0, stream>>>(kvp, ksp, kvt, ksum);
  num_mfma<<<dim3(32, 64), 256, 0, stream>>>(qb, kvt, ksum, attn);
  gemm256<1><<<dim3(4, 64), 512, 0, stream>>>(attn, wprojb, b_proj, nullptr, nullptr, nullptr, out, 1024);
}

// Round 2
// 316.658 us; speedup vs baseline: 1.2100x; 1.0520x over previous
//
#include <hip/hip_runtime.h>
#include <hip/hip_bf16.h>
#include <stdint.h>

typedef __hip_bfloat16 bf16;
typedef __attribute__((ext_vector_type(4))) float f32x4;
typedef __attribute__((ext_vector_type(8))) short short8;

#define SEQ   4096
#define CDIM  1024

// ---------------------------------------------------------------------------
// async global->LDS, 16B per lane. LDS dest = wave-uniform base + lane*16.
// ---------------------------------------------------------------------------
__device__ __forceinline__ void async_load16(const void* g, void* l) {
  auto gp = reinterpret_cast<const __attribute__((address_space(1))) uint32_t*>(
      reinterpret_cast<uintptr_t>(g));
  auto lp = reinterpret_cast<__attribute__((address_space(3))) uint32_t*>(
      static_cast<uint32_t>(reinterpret_cast<uintptr_t>(l)));
  __builtin_amdgcn_global_load_lds(gp, lp, 16, 0, 0);
}

// ---------------------------------------------------------------------------
// fused fp32 -> bf16 convert for x, w_qkv, w_proj (one launch)
// ---------------------------------------------------------------------------
__global__ __launch_bounds__(256) void convert3_kernel(const float* __restrict__ x,
                                                       const float* __restrict__ wq,
                                                       const float* __restrict__ wp,
                                                       bf16* __restrict__ xb,
                                                       bf16* __restrict__ wqb,
                                                       bf16* __restrict__ wpb) {
  int i = blockIdx.x * 256 + threadIdx.x;
  const float* src;
  bf16* dst;
  int off;
  if (i < 4194304)      { src = x;  dst = xb;  off = i; }
  else if (i < 4980736) { src = wq; dst = wqb; off = i - 4194304; }
  else                  { src = wp; dst = wpb; off = i - 4980736; }
  float4 f = ((const float4*)src)[off];
  union { bf16 b[4]; ushort4 u; } c;
  c.b[0] = __float2bfloat16(f.x);
  c.b[1] = __float2bfloat16(f.y);
  c.b[2] = __float2bfloat16(f.z);
  c.b[3] = __float2bfloat16(f.w);
  ((ushort4*)dst)[off] = c.u;
}

// ---------------------------------------------------------------------------
// 256x256 8-phase bf16 GEMM (T2 swizzle + T3/T4 counted vmcnt + T5 setprio).
//   C[m][n] = sum_k A[m][k] * B[n][k]   (both row-major, K-contiguous)
// 512 threads = 8 waves (2M x 4N); per-wave output 128x64; BK=64.
// LDS: A0,B0,A1,B1 each [256][64] bf16 = 4 x 32 KiB = 128 KiB.
// T2 swizzle (full 3-bit form): LDS[row][c] holds global[row][c ^ ((row&7)*8)],
// achieved by pre-swizzling the per-lane GLOBAL source chunk
// (cs = ((lane&7)^(lane>>3))<<3 — lane covers row base+(lane>>3), chunk lane&7)
// while the LDS dest stays linear (global_load_lds constraint). Reads apply
// the same XOR (sw = (lr&7)<<3). Every fragment-read row has row&7 == lr&7.
// Bank check: read quad = lq ^ (lr&7) -> all 8 slots covered, 8 lanes/quad
// (theoretical minimum for a 1024B wave read).
// Staging stream: the half-tile staged in phase p is the region last read in
// phase p-1 -> vmcnt(6) at phases 4 and 8 is sufficient.
// ---------------------------------------------------------------------------
#define BARR()  __builtin_amdgcn_s_barrier()
#define LGKM0() asm volatile("s_waitcnt lgkmcnt(0)" ::: "memory")
#define VMW6()  asm volatile("s_waitcnt vmcnt(6)" ::: "memory")
#define VMW0()  asm volatile("s_waitcnt vmcnt(0)" ::: "memory")
#define SP(x)   __builtin_amdgcn_s_setprio(x)

// A half h: rows {h*64 + [0,64)} u {h*64+128 + [0,64)}; wave w stages 8 rows.
#define STA(buf, kc, h)                                                        \
  {                                                                            \
    const int ra_ = (h) * 64 + w * 8;                                          \
    async_load16(Ag + (size_t)(ra_ + lr8) * K + (kc) + cs, (buf) + ra_ * 64);  \
    async_load16(Ag + (size_t)(ra_ + 128 + lr8) * K + (kc) + cs,               \
                 (buf) + (ra_ + 128) * 64);                                    \
  }
// B half h: rows {wn'*64 + h*32 + [0,32) : wn'=0..3}; wave w stages 8 rows.
#define STB(buf, kc, h)                                                        \
  {                                                                            \
    const int rb_ = (w & 3) * 8 + (w >> 2) * 64 + (h) * 32;                    \
    async_load16(Bg + (size_t)(rb_ + lr8) * K + (kc) + cs, (buf) + rb_ * 64);  \
    async_load16(Bg + (size_t)(rb_ + 128 + lr8) * K + (kc) + cs,               \
                 (buf) + (rb_ + 128) * 64);                                    \
  }

#define RD_A(buf, h)                                                           \
  {                                                                            \
    _Pragma("unroll") for (int mi = 0; mi < 4; ++mi) {                         \
      const unsigned short* p_ = (buf) + (arow0 + (h) * 64 + mi * 16) * 64;    \
      af[mi][0] = *(const short8*)(p_ + ((lq * 8) ^ sw));                      \
      af[mi][1] = *(const short8*)(p_ + ((32 + lq * 8) ^ sw));                 \
    }                                                                          \
  }
#define RD_B(buf, h)                                                           \
  {                                                                            \
    _Pragma("unroll") for (int ni = 0; ni < 2; ++ni) {                         \
      const unsigned short* p_ = (buf) + (brow0 + (h) * 32 + ni * 16) * 64;    \
      bfr[ni][0] = *(const short8*)(p_ + ((lq * 8) ^ sw));                     \
      bfr[ni][1] = *(const short8*)(p_ + ((32 + lq * 8) ^ sw));                \
    }                                                                          \
  }

#define MMA(MQ, NQ)                                                            \
  {                                                                            \
    _Pragma("unroll") for (int ks = 0; ks < 2; ++ks)                           \
      _Pragma("unroll") for (int mi = 0; mi < 4; ++mi)                         \
        _Pragma("unroll") for (int ni = 0; ni < 2; ++ni)                       \
          acc[(MQ) * 4 + mi][(NQ) * 2 + ni] =                                  \
              __builtin_amdgcn_mfma_f32_16x16x32_bf16(                         \
                  af[mi][ks], bfr[ni][ks], acc[(MQ) * 4 + mi][(NQ) * 2 + ni],  \
                  0, 0, 0);                                                    \
  }

// one full iteration: compute tiles (kc)/buf0 [ph1-4] and (kc+64)/buf1 [ph5-8]
// while staging tiles kc+128 (buf0) and kc+192 (buf1) + Bh0(buf1,kc+64) at ph1.
#define FULL_ITER(kc)                                                          \
  RD_A(A0, 0); RD_B(B0, 0); STB(B1, (kc) + 64, 0);                             \
  BARR(); LGKM0(); SP(1); MMA(0, 0); SP(0); BARR();                            \
  RD_B(B0, 1); STA(A0, (kc) + 128, 0);                                         \
  BARR(); LGKM0(); SP(1); MMA(0, 1); SP(0); BARR();                            \
  RD_A(A0, 1); STB(B0, (kc) + 128, 1);                                         \
  BARR(); LGKM0(); SP(1); MMA(1, 1); SP(0); BARR();                            \
  RD_B(B0, 0); STA(A0, (kc) + 128, 1); VMW6();                                 \
  BARR(); LGKM0(); SP(1); MMA(1, 0); SP(0); BARR();                            \
  RD_A(A1, 0); RD_B(B1, 0); STB(B0, (kc) + 128, 0);                            \
  BARR(); LGKM0(); SP(1); MMA(0, 0); SP(0); BARR();                            \
  RD_B(B1, 1); STA(A1, (kc) + 192, 0);                                         \
  BARR(); LGKM0(); SP(1); MMA(0, 1); SP(0); BARR();                            \
  RD_A(A1, 1); STB(B1, (kc) + 192, 1);                                         \
  BARR(); LGKM0(); SP(1); MMA(1, 1); SP(0); BARR();                            \
  RD_B(B1, 0); STA(A1, (kc) + 192, 1); VMW6();                                 \
  BARR(); LGKM0(); SP(1); MMA(1, 0); SP(0); BARR();

// last iteration: only Bh0(buf1) still needs staging; drain with vmcnt(0).
#define FINAL_ITER(kc)                                                         \
  RD_A(A0, 0); RD_B(B0, 0); STB(B1, (kc) + 64, 0);                             \
  BARR(); LGKM0(); SP(1); MMA(0, 0); SP(0); BARR();                            \
  RD_B(B0, 1);                                                                 \
  BARR(); LGKM0(); SP(1); MMA(0, 1); SP(0); BARR();                            \
  RD_A(A0, 1);                                                                 \
  BARR(); LGKM0(); SP(1); MMA(1, 1); SP(0); BARR();                            \
  RD_B(B0, 0); VMW0();                                                         \
  BARR(); LGKM0(); SP(1); MMA(1, 0); SP(0); BARR();                            \
  RD_A(A1, 0); RD_B(B1, 0);                                                    \
  BARR(); LGKM0(); SP(1); MMA(0, 0); SP(0); BARR();                            \
  RD_B(B1, 1);                                                                 \
  BARR(); LGKM0(); SP(1); MMA(0, 1); SP(0); BARR();                            \
  RD_A(A1, 1);                                                                 \
  BARR(); LGKM0(); SP(1); MMA(1, 1); SP(0); BARR();                            \
  RD_B(B1, 0);                                                                 \
  LGKM0(); SP(1); MMA(1, 0); SP(0);

template <int EPI>
__global__ __launch_bounds__(512, 2) void gemm256(const bf16* __restrict__ X,
                                                  const bf16* __restrict__ W,
                                                  const float* __restrict__ bias,
                                                  bf16* __restrict__ Qo,
                                                  bf16* __restrict__ Ko,
                                                  bf16* __restrict__ Vo,
                                                  float* __restrict__ Out,
                                                  const int K) {
  __shared__ __attribute__((aligned(16))) unsigned short lds[4][256 * 64];
  unsigned short* const A0 = lds[0];
  unsigned short* const B0 = lds[1];
  unsigned short* const A1 = lds[2];
  unsigned short* const B1 = lds[3];

  const int tid  = threadIdx.x;
  const int w    = tid >> 6, lane = tid & 63;
  const int wm   = w >> 2,   wn   = w & 3;
  const int lr   = lane & 15, lq  = lane >> 4;
  const int bm   = blockIdx.y, bn = blockIdx.x;
  const int sw   = (lr & 7) << 3;                          // read-side XOR (elems)
  const int cs   = (((lane & 7) ^ (lane >> 3)) << 3);      // src-side pre-swizzle
  const int lr8  = lane >> 3;

  const bool swapped = (EPI == 0) && (bn < 4);
  const bf16* Xg = X + (size_t)(bm * 256) * K;
  const bf16* Wg = W + (size_t)(bn * 256) * K;
  const bf16* Ag = swapped ? Wg : Xg;
  const bf16* Bg = swapped ? Xg : Wg;

  const int arow0 = wm * 128 + lr;
  const int brow0 = wn * 64 + lr;

  short8 af[4][2], bfr[2][2];
  f32x4 acc[8][4] = {};

  // prologue: buf0 tile0 fully; buf1 tile1 {Ah0,Bh1,Ah1} (Bh0(b1) comes at ph1)
  STA(A0, 0, 0);
  STB(B0, 0, 0);
  STB(B0, 0, 1);
  STA(A0, 0, 1);
  STA(A1, 64, 0);
  STB(B1, 64, 1);
  STA(A1, 64, 1);
  VMW6();            // first 4 half-tiles (all of buf0) landed
  BARR();

#pragma unroll 1
  for (int kc = 0; kc < K - 128; kc += 128) {
    FULL_ITER(kc);
  }
  FINAL_ITER(K - 128);

  // ------------------------- epilogue -------------------------
  if constexpr (EPI == 0) {
    if (swapped) {
      // Q block: m = channel j, col = token t. 4 regs = 4 consecutive d.
#pragma unroll
      for (int mt = 0; mt < 8; ++mt) {
        const int j0 = bn * 256 + wm * 128 + mt * 16 + lq * 4;
        const int h  = j0 >> 6, d0 = j0 & 63;
#pragma unroll
        for (int nt = 0; nt < 4; ++nt) {
          const int t = bm * 256 + wn * 64 + nt * 16 + lr;
          const int b = t >> 12, n = t & 4095;
          union { bf16 v[4]; ushort4 u; } pk;
#pragma unroll
          for (int r = 0; r < 4; ++r) {
            float v = acc[mt][nt][r];
            v = (v > 0.0f) ? (v + 1.0f) : __expf(v);
            pk.v[r] = __float2bfloat16(v);
          }
          *(ushort4*)(Qo + (((size_t)((b * 16 + h) * SEQ + n)) << 6) + d0) = pk.u;
        }
      }
    } else {
      // K/V block: m = token t, col = channel j. 4 regs = 4 consecutive n.
#pragma unroll
      for (int nt = 0; nt < 4; ++nt) {
        const int j   = bn * 256 + wn * 64 + nt * 16 + lr;
        const int sel = j >> 10;           // 1 = K, 2 = V
        const int h   = (j >> 6) & 15;
        const int d   = j & 63;
        bf16* dst = (sel == 1) ? Ko : Vo;
#pragma unroll
        for (int mt = 0; mt < 8; ++mt) {
          const int t0 = bm * 256 + wm * 128 + mt * 16 + lq * 4;
          const int b = t0 >> 12, n0 = t0 & 4095;
          union { bf16 v[4]; ushort4 u; } pk;
#pragma unroll
          for (int r = 0; r < 4; ++r) {
            float v = acc[mt][nt][r];
            if (sel == 1) v = (v > 0.0f) ? (v + 1.0f) : __expf(v);
            pk.v[r] = __float2bfloat16(v);
          }
          *(ushort4*)(dst + ((size_t)((b * 16 + h) * 64 + d)) * SEQ + n0) = pk.u;
        }
      }
    }
  } else {
    // proj: m = token t, col = channel. Coalesced scalar fp32 stores + bias.
#pragma unroll
    for (int mt = 0; mt < 8; ++mt) {
#pragma unroll
      for (int r = 0; r < 4; ++r) {
        const int t = bm * 256 + wm * 128 + mt * 16 + lq * 4 + r;
        float* op = Out + (size_t)t * CDIM + bn * 256 + wn * 64 + lr;
#pragma unroll
        for (int nt = 0; nt < 4; ++nt)
          op[nt * 16] = acc[mt][nt][r] + bias[bn * 256 + wn * 64 + nt * 16 + lr];
      }
    }
  }
}

// ---------------------------------------------------------------------------
// kv partials via MFMA.  Inputs K^T,V^T [bh][d][n] (n contiguous).
// Same T2 involution: LDS[row][c] = global[row][c ^ ((row&7)*8)].
// ---------------------------------------------------------------------------
__global__ __launch_bounds__(256) void kv_mfma(const bf16* __restrict__ KT,
                                               const bf16* __restrict__ VT,
                                               float* __restrict__ KVp,
                                               float* __restrict__ KSp) {
  __shared__ bf16 kt[64 * 64];
  __shared__ bf16 vt[64 * 64];
  const int tid = threadIdx.x;
  const int w = tid >> 6, lane = tid & 63;
  const int wm = w >> 1, wn = w & 1;
  const int lr = lane & 15, lq = lane >> 4;
  const int swz = (lr & 7) * 8;                            // read-side XOR
  const int csz = (((lane & 7) ^ (lane >> 3)) * 8);        // src-side pre-swizzle
  const int sp = blockIdx.x, bh = blockIdx.y;
  const bf16* kg0 = KT + (size_t)bh * 64 * SEQ + sp * 512;
  const bf16* vg0 = VT + (size_t)bh * 64 * SEQ + sp * 512;

  f32x4 acc[2][2] = {};
  f32x4 kacc0 = {}, kacc1 = {};
  short8 ones;
#pragma unroll
  for (int j = 0; j < 8; ++j) ((unsigned short*)&ones)[j] = 0x3F80;  // bf16 1.0

  for (int nc = 0; nc < 8; ++nc) {
    __syncthreads();
#pragma unroll
    for (int i = 0; i < 2; ++i) {
      const int row = w * 16 + i * 8 + (lane >> 3);
      async_load16(kg0 + (size_t)row * SEQ + nc * 64 + csz, kt + (w * 16 + i * 8) * 64);
      async_load16(vg0 + (size_t)row * SEQ + nc * 64 + csz, vt + (w * 16 + i * 8) * 64);
    }
    __syncthreads();

#pragma unroll
    for (int ks = 0; ks < 2; ++ks) {
      short8 a0 = *(const short8*)&kt[(wm * 32 +      lr) * 64 + ((ks * 32 + lq * 8) ^ swz)];
      short8 a1 = *(const short8*)&kt[(wm * 32 + 16 + lr) * 64 + ((ks * 32 + lq * 8) ^ swz)];
      short8 b0 = *(const short8*)&vt[(wn * 32 +      lr) * 64 + ((ks * 32 + lq * 8) ^ swz)];
      short8 b1 = *(const short8*)&vt[(wn * 32 + 16 + lr) * 64 + ((ks * 32 + lq * 8) ^ swz)];
      acc[0][0] = __builtin_amdgcn_mfma_f32_16x16x32_bf16(a0, b0, acc[0][0], 0, 0, 0);
      acc[0][1] = __builtin_amdgcn_mfma_f32_16x16x32_bf16(a0, b1, acc[0][1], 0, 0, 0);
      acc[1][0] = __builtin_amdgcn_mfma_f32_16x16x32_bf16(a1, b0, acc[1][0], 0, 0, 0);
      acc[1][1] = __builtin_amdgcn_mfma_f32_16x16x32_bf16(a1, b1, acc[1][1], 0, 0, 0);
      kacc0 = __builtin_amdgcn_mfma_f32_16x16x32_bf16(a0, ones, kacc0, 0, 0, 0);
      kacc1 = __builtin_amdgcn_mfma_f32_16x16x32_bf16(a1, ones, kacc1, 0, 0, 0);
    }
  }

  float* outp = KVp + ((size_t)(sp * 64 + bh)) * 4096;
#pragma unroll
  for (int mt = 0; mt < 2; ++mt)
#pragma unroll
    for (int nt = 0; nt < 2; ++nt) {
      const int e  = wn * 32 + nt * 16 + lr;
      const int d0 = wm * 32 + mt * 16 + lq * 4;
      *(float4*)&outp[e * 64 + d0] = *(float4*)&acc[mt][nt];
    }
  if (wn == 0 && lr == 0) {
    float* ksp = KSp + (size_t)(sp * 64 + bh) * 64 + wm * 32;
#pragma unroll
    for (int r = 0; r < 4; ++r) {
      ksp[lq * 4 + r]      = kacc0[r];
      ksp[16 + lq * 4 + r] = kacc1[r];
    }
  }
}

// ---------------------------------------------------------------------------
__global__ __launch_bounds__(256) void kv_reduce(const float* __restrict__ KVp,
                                                 const float* __restrict__ KSp,
                                                 bf16* __restrict__ KVT,
                                                 float* __restrict__ KS) {
  const int bh = blockIdx.x, t = threadIdx.x;
#pragma unroll 4
  for (int i = 0; i < 16; ++i) {
    const int idx = i * 256 + t;
    float s = 0.0f;
#pragma unroll
    for (int sp = 0; sp < 8; ++sp) s += KVp[((size_t)(sp * 64 + bh)) * 4096 + idx];
    const bf16 hi = __float2bfloat16(s);
    const float lo = s - __bfloat162float(hi);
    const int e = idx >> 6, d = idx & 63;
    KVT[(size_t)bh * 8192 + e * 128 + d]      = hi;
    KVT[(size_t)bh * 8192 + e * 128 + 64 + d] = __float2bfloat16(lo);
  }
  if (t < 64) {
    float s = 0.0f;
#pragma unroll
    for (int sp = 0; sp < 8; ++sp) s += KSp[(sp * 64 + bh) * 64 + t];
    KS[bh * 64 + t] = s;
  }
}

// ---------------------------------------------------------------------------
// num = q @ kv. qs [128][64] and kvs [64][128] both carry the T2 involution
// LDS[row][c] = global[row][c ^ ((row&7)*8)] (chunk-granular, 8-elem chunks).
// ---------------------------------------------------------------------------
__global__ __launch_bounds__(256) void num_mfma(const bf16* __restrict__ Qb,
                                                const bf16* __restrict__ KVT,
                                                const float* __restrict__ KS,
                                                bf16* __restrict__ Attn) {
  __shared__ bf16 qs[128 * 64];
  __shared__ bf16 kvs[64 * 128];
  __shared__ bf16 Cs[128 * 72];
  __shared__ float ksl[64];
  __shared__ float dred[256];
  __shared__ float den[128];
  const int tid = threadIdx.x;
  const int w = tid >> 6, lane = tid & 63;
  const int wm = w >> 1, wn = w & 1;
  const int lr = lane & 15, lq = lane >> 4;
  const int swz = (lr & 7) * 8;
  const int bh = blockIdx.y, n00 = blockIdx.x * 128;
  const int b = bh >> 4, h = bh & 15;

  const bf16* qg  = Qb  + ((size_t)bh * SEQ + n00) * 64;
  const bf16* kvg = KVT + (size_t)bh * 8192;
  // qs: lane covers row base+(lane>>3), chunk lane&7 -> src chunk ^= row&7
  const int qcs = (((lane & 7) ^ (lane >> 3)) * 8);
#pragma unroll
  for (int i = 0; i < 4; ++i) {
    const int row = w * 32 + i * 8 + (lane >> 3);
    async_load16(qg + (size_t)row * 64 + qcs, qs + (w * 32 + i * 8) * 64);
  }
  // kvs: lane covers row base+(lane>>4), chunk lane&15 (128-elem rows)
#pragma unroll
  for (int i = 0; i < 4; ++i) {
    const int row = w * 16 + i * 4 + (lane >> 4);
    const int scol = (((lane & 15) * 8) ^ ((row & 7) * 8));
    async_load16(kvg + (size_t)row * 128 + scol, kvs + (w * 16 + i * 4) * 128);
  }
  if (tid < 64) ksl[tid] = KS[bh * 64 + tid];
  __syncthreads();

  {
    const int n = tid >> 1, half = tid & 1;
    const int nsw = (n & 7) * 8;
    float s = 0.0f;
#pragma unroll
    for (int v8 = 0; v8 < 4; ++v8) {
      short8 qq = *(const short8*)&qs[n * 64 + ((half * 32 + v8 * 8) ^ nsw)];
#pragma unroll
      for (int j = 0; j < 8; ++j)
        s += __bfloat162float(((const bf16*)&qq)[j]) * ksl[half * 32 + v8 * 8 + j];
    }
    dred[tid] = s;
  }

  short8 afr[4][2], bfr2[2][4];
#pragma unroll
  for (int mt = 0; mt < 4; ++mt)
#pragma unroll
    for (int kh = 0; kh < 2; ++kh)
      afr[mt][kh] = *(const short8*)&qs[(wm * 64 + mt * 16 + lr) * 64 + ((kh * 32 + lq * 8) ^ swz)];
#pragma unroll
  for (int nt = 0; nt < 2; ++nt)
#pragma unroll
    for (int ks = 0; ks < 4; ++ks)
      bfr2[nt][ks] = *(const short8*)&kvs[(wn * 32 + nt * 16 + lr) * 128 + ((ks * 32 + lq * 8) ^ swz)];

  f32x4 acc[4][2] = {};
#pragma unroll
  for (int ks = 0; ks < 4; ++ks)
#pragma unroll
    for (int mt = 0; mt < 4; ++mt)
#pragma unroll
      for (int nt = 0; nt < 2; ++nt)
        acc[mt][nt] = __builtin_amdgcn_mfma_f32_16x16x32_bf16(afr[mt][ks & 1], bfr2[nt][ks],
                                                              acc[mt][nt], 0, 0, 0);
  __syncthreads();
  if (tid < 128) den[tid] = dred[tid * 2] + dred[tid * 2 + 1] + 1e-8f;
  __syncthreads();

#pragma unroll
  for (int mt = 0; mt < 4; ++mt) {
#pragma unroll
    for (int r = 0; r < 4; ++r) {
      const int nl = wm * 64 + mt * 16 + lq * 4 + r;
      const float inv = 1.0f / den[nl];
#pragma unroll
      for (int nt = 0; nt < 2; ++nt) {
        const int e = wn * 32 + nt * 16 + lr;
        Cs[nl * 72 + e] = __float2bfloat16(acc[mt][nt][r] * inv);
      }
    }
  }
  __syncthreads();
#pragma unroll
  for (int it = 0; it < 4; ++it) {
    const int nl = it * 32 + (tid >> 3);
    const int ch = tid & 7;
    short8 val = *(const short8*)&Cs[nl * 72 + ch * 8];
    *(short8*)(Attn + ((size_t)(b * SEQ + n00 + nl)) * CDIM + h * 64 + ch * 8) = val;
  }
}

// ---------------------------------------------------------------------------
extern "C" void kernel_launch(void* const* d_in, const int* in_sizes, int n_in,
                              void* d_out, int out_size, void* d_ws, size_t ws_size,
                              hipStream_t stream) {
  const float* x      = (const float*)d_in[0];
  const float* w_qkv  = (const float*)d_in[1];
  const float* w_proj = (const float*)d_in[2];
  const float* b_proj = (const float*)d_in[3];
  float* out = (float*)d_out;
  char* ws = (char*)d_ws;

  bf16*  xb     = (bf16*)(ws + 0);
  bf16*  wqkvb  = (bf16*)(ws + 33554432);
  bf16*  wprojb = (bf16*)(ws + 39845888);
  bf16*  qb     = (bf16*)(ws + 41943040);
  bf16*  ktb    = (bf16*)(ws + 75497472);
  bf16*  vtb    = (bf16*)(ws + 109051904);
  float* kvp    = (float*)(ws + 0);
  float* ksp    = (float*)(ws + 8388608);
  bf16*  kvt    = (bf16*)(ws + 142606336);
  float* ksum   = (float*)(ws + 143654912);
  bf16*  attn   = (bf16*)(ws + 0);

  convert3_kernel<<<20480, 256, 0, stream>>>(x, w_qkv, w_proj, xb, wqkvb, wprojb);

  gemm256<0><<<dim3(12, 64), 512, 0, stream>>>(xb, wqkvb, nullptr, qb, ktb, vtb, nullptr, 1024);
  kv_mfma<<<dim3(8, 64), 256, 0, stream>>>(ktb, vtb, kvp, ksp);
  kv_reduce<<<64, 256, 0, stream>>>(kvp, ksp, kvt, ksum);
  num_mfma<<<dim3(32, 64), 256, 0, stream>>>(qb, kvt, ksum, attn);
  gemm256<1><<<dim3(4, 64), 512, 0, stream>>>(attn, wprojb, b_proj, nullptr, nullptr, nullptr, out, 1024);
}

// Round 3
// 304.903 us; speedup vs baseline: 1.2566x; 1.0386x over previous
//
#include <hip/hip_runtime.h>
#include <hip/hip_bf16.h>
#include <stdint.h>

typedef __hip_bfloat16 bf16;
typedef __attribute__((ext_vector_type(4))) float f32x4;
typedef __attribute__((ext_vector_type(8))) short short8;

#define SEQ   4096
#define CDIM  1024

// ---------------------------------------------------------------------------
// async global->LDS, 16B per lane. LDS dest = wave-uniform base + lane*16.
// ---------------------------------------------------------------------------
__device__ __forceinline__ void async_load16(const void* g, void* l) {
  auto gp = reinterpret_cast<const __attribute__((address_space(1))) uint32_t*>(
      reinterpret_cast<uintptr_t>(g));
  auto lp = reinterpret_cast<__attribute__((address_space(3))) uint32_t*>(
      static_cast<uint32_t>(reinterpret_cast<uintptr_t>(l)));
  __builtin_amdgcn_global_load_lds(gp, lp, 16, 0, 0);
}

// ---------------------------------------------------------------------------
// fused fp32 -> bf16 convert for x, w_qkv, w_proj (one launch)
// ---------------------------------------------------------------------------
__global__ __launch_bounds__(256) void convert3_kernel(const float* __restrict__ x,
                                                       const float* __restrict__ wq,
                                                       const float* __restrict__ wp,
                                                       bf16* __restrict__ xb,
                                                       bf16* __restrict__ wqb,
                                                       bf16* __restrict__ wpb) {
  int i = blockIdx.x * 256 + threadIdx.x;
  const float* src;
  bf16* dst;
  int off;
  if (i < 4194304)      { src = x;  dst = xb;  off = i; }
  else if (i < 4980736) { src = wq; dst = wqb; off = i - 4194304; }
  else                  { src = wp; dst = wpb; off = i - 4980736; }
  float4 f = ((const float4*)src)[off];
  union { bf16 b[4]; ushort4 u; } c;
  c.b[0] = __float2bfloat16(f.x);
  c.b[1] = __float2bfloat16(f.y);
  c.b[2] = __float2bfloat16(f.z);
  c.b[3] = __float2bfloat16(f.w);
  ((ushort4*)dst)[off] = c.u;
}

// ---------------------------------------------------------------------------
// 256x256 8-phase bf16 GEMM (T2 swizzle + T3/T4 counted vmcnt + T5 setprio
// + T1 XCD-chunked block swizzle).
//   C[m][n] = sum_k A[m][k] * B[n][k]   (both row-major, K-contiguous)
// 512 threads = 8 waves (2M x 4N); per-wave output 128x64; BK=64.
// LDS: A0,B0,A1,B1 each [256][64] bf16 = 4 x 32 KiB = 128 KiB.
// T2: LDS[row][c] = global[row][c ^ ((row&7)*8)], via pre-swizzled global
// source (linear LDS dest) + matching XOR on ds_read. Bank check: read
// quad = lq ^ (lr&7) -> 8 slots covered, 8 lanes/quad (minimum).
// Phase read plan per K-tile (no B re-read; both B-halves held in regs):
//   ph1: RD_A(h0)+RD_B(h0)=12  ph2: RD_B(h1)=4  ph3: RD_A(h1)=8  ph4: none
// Staging placement unchanged -> vmcnt(6) at ph4/ph8 still exact.
// ---------------------------------------------------------------------------
#define BARR()  __builtin_amdgcn_s_barrier()
#define LGKM0() asm volatile("s_waitcnt lgkmcnt(0)" ::: "memory")
#define VMW6()  asm volatile("s_waitcnt vmcnt(6)" ::: "memory")
#define VMW0()  asm volatile("s_waitcnt vmcnt(0)" ::: "memory")
#define SP(x)   __builtin_amdgcn_s_setprio(x)

// A half h: rows {h*64 + [0,64)} u {h*64+128 + [0,64)}; wave w stages 8 rows.
#define STA(buf, kc, h)                                                        \
  {                                                                            \
    const int ra_ = (h) * 64 + w * 8;                                          \
    async_load16(Ag + (size_t)(ra_ + lr8) * K + (kc) + cs, (buf) + ra_ * 64);  \
    async_load16(Ag + (size_t)(ra_ + 128 + lr8) * K + (kc) + cs,               \
                 (buf) + (ra_ + 128) * 64);                                    \
  }
// B half h: rows {wn'*64 + h*32 + [0,32) : wn'=0..3}; wave w stages 8 rows.
#define STB(buf, kc, h)                                                        \
  {                                                                            \
    const int rb_ = (w & 3) * 8 + (w >> 2) * 64 + (h) * 32;                    \
    async_load16(Bg + (size_t)(rb_ + lr8) * K + (kc) + cs, (buf) + rb_ * 64);  \
    async_load16(Bg + (size_t)(rb_ + 128 + lr8) * K + (kc) + cs,               \
                 (buf) + (rb_ + 128) * 64);                                    \
  }

#define RD_A(buf, h)                                                           \
  {                                                                            \
    _Pragma("unroll") for (int mi = 0; mi < 4; ++mi) {                         \
      const unsigned short* p_ = (buf) + (arow0 + (h) * 64 + mi * 16) * 64;    \
      af[mi][0] = *(const short8*)(p_ + ((lq * 8) ^ sw));                      \
      af[mi][1] = *(const short8*)(p_ + ((32 + lq * 8) ^ sw));                 \
    }                                                                          \
  }
#define RD_B(buf, h)                                                           \
  {                                                                            \
    _Pragma("unroll") for (int ni = 0; ni < 2; ++ni) {                         \
      const unsigned short* p_ = (buf) + (brow0 + (h) * 32 + ni * 16) * 64;    \
      bfr[h][ni][0] = *(const short8*)(p_ + ((lq * 8) ^ sw));                  \
      bfr[h][ni][1] = *(const short8*)(p_ + ((32 + lq * 8) ^ sw));             \
    }                                                                          \
  }

#define MMA(MQ, NQ)                                                            \
  {                                                                            \
    _Pragma("unroll") for (int ks = 0; ks < 2; ++ks)                           \
      _Pragma("unroll") for (int mi = 0; mi < 4; ++mi)                         \
        _Pragma("unroll") for (int ni = 0; ni < 2; ++ni)                       \
          acc[(MQ) * 4 + mi][(NQ) * 2 + ni] =                                  \
              __builtin_amdgcn_mfma_f32_16x16x32_bf16(                         \
                  af[mi][ks], bfr[NQ][ni][ks],                                 \
                  acc[(MQ) * 4 + mi][(NQ) * 2 + ni], 0, 0, 0);                 \
  }

// one full iteration: compute tiles (kc)/buf0 [ph1-4] and (kc+64)/buf1 [ph5-8]
// while staging tiles kc+128 (buf0) and kc+192 (buf1) + Bh0(buf1,kc+64) at ph1.
#define FULL_ITER(kc)                                                          \
  RD_A(A0, 0); RD_B(B0, 0); STB(B1, (kc) + 64, 0);                             \
  BARR(); LGKM0(); SP(1); MMA(0, 0); SP(0); BARR();                            \
  RD_B(B0, 1); STA(A0, (kc) + 128, 0);                                         \
  BARR(); LGKM0(); SP(1); MMA(0, 1); SP(0); BARR();                            \
  RD_A(A0, 1); STB(B0, (kc) + 128, 1);                                         \
  BARR(); LGKM0(); SP(1); MMA(1, 1); SP(0); BARR();                            \
  STA(A0, (kc) + 128, 1); VMW6();                                              \
  BARR(); SP(1); MMA(1, 0); SP(0); BARR();                                     \
  RD_A(A1, 0); RD_B(B1, 0); STB(B0, (kc) + 128, 0);                            \
  BARR(); LGKM0(); SP(1); MMA(0, 0); SP(0); BARR();                            \
  RD_B(B1, 1); STA(A1, (kc) + 192, 0);                                         \
  BARR(); LGKM0(); SP(1); MMA(0, 1); SP(0); BARR();                            \
  RD_A(A1, 1); STB(B1, (kc) + 192, 1);                                         \
  BARR(); LGKM0(); SP(1); MMA(1, 1); SP(0); BARR();                            \
  STA(A1, (kc) + 192, 1); VMW6();                                              \
  BARR(); SP(1); MMA(1, 0); SP(0); BARR();

// last iteration: only Bh0(buf1) still needs staging; drain with vmcnt(0).
#define FINAL_ITER(kc)                                                         \
  RD_A(A0, 0); RD_B(B0, 0); STB(B1, (kc) + 64, 0);                             \
  BARR(); LGKM0(); SP(1); MMA(0, 0); SP(0); BARR();                            \
  RD_B(B0, 1);                                                                 \
  BARR(); LGKM0(); SP(1); MMA(0, 1); SP(0); BARR();                            \
  RD_A(A0, 1);                                                                 \
  BARR(); LGKM0(); SP(1); MMA(1, 1); SP(0); BARR();                            \
  VMW0();                                                                      \
  BARR(); SP(1); MMA(1, 0); SP(0); BARR();                                     \
  RD_A(A1, 0); RD_B(B1, 0);                                                    \
  BARR(); LGKM0(); SP(1); MMA(0, 0); SP(0); BARR();                            \
  RD_B(B1, 1);                                                                 \
  BARR(); LGKM0(); SP(1); MMA(0, 1); SP(0); BARR();                            \
  RD_A(A1, 1);                                                                 \
  BARR(); LGKM0(); SP(1); MMA(1, 1); SP(0); BARR();                            \
  SP(1); MMA(1, 0); SP(0);

template <int EPI>
__global__ __launch_bounds__(512, 2) void gemm256(const bf16* __restrict__ X,
                                                  const bf16* __restrict__ W,
                                                  const float* __restrict__ bias,
                                                  bf16* __restrict__ Qo,
                                                  bf16* __restrict__ Ko,
                                                  bf16* __restrict__ Vo,
                                                  float* __restrict__ Out,
                                                  const int K) {
  __shared__ __attribute__((aligned(16))) unsigned short lds[4][256 * 64];
  unsigned short* const A0 = lds[0];
  unsigned short* const B0 = lds[1];
  unsigned short* const A1 = lds[2];
  unsigned short* const B1 = lds[3];

  const int tid  = threadIdx.x;
  const int w    = tid >> 6, lane = tid & 63;
  const int wm   = w >> 2,   wn   = w & 3;
  const int lr   = lane & 15, lq  = lane >> 4;

  // T1: XCD-chunked bijective remap (nwg % 8 == 0 for both grids).
  const int GX   = (int)gridDim.x;
  const int nwg  = GX * (int)gridDim.y;
  const int lin  = (int)blockIdx.y * GX + (int)blockIdx.x;
  const int tile = (lin & 7) * (nwg >> 3) + (lin >> 3);
  const int bn   = tile % GX;
  const int bm   = tile / GX;

  const int sw   = (lr & 7) << 3;                          // read-side XOR (elems)
  const int cs   = (((lane & 7) ^ (lane >> 3)) << 3);      // src-side pre-swizzle
  const int lr8  = lane >> 3;

  const bool swapped = (EPI == 0) && (bn < 4);
  const bf16* Xg = X + (size_t)(bm * 256) * K;
  const bf16* Wg = W + (size_t)(bn * 256) * K;
  const bf16* Ag = swapped ? Wg : Xg;
  const bf16* Bg = swapped ? Xg : Wg;

  const int arow0 = wm * 128 + lr;
  const int brow0 = wn * 64 + lr;

  short8 af[4][2], bfr[2][2][2];   // bfr[half][ni][ks]
  f32x4 acc[8][4] = {};

  // prologue: buf0 tile0 fully; buf1 tile1 {Ah0,Bh1,Ah1} (Bh0(b1) comes at ph1)
  STA(A0, 0, 0);
  STB(B0, 0, 0);
  STB(B0, 0, 1);
  STA(A0, 0, 1);
  STA(A1, 64, 0);
  STB(B1, 64, 1);
  STA(A1, 64, 1);
  VMW6();            // first 4 half-tiles (all of buf0) landed
  BARR();

#pragma unroll 1
  for (int kc = 0; kc < K - 128; kc += 128) {
    FULL_ITER(kc);
  }
  FINAL_ITER(K - 128);

  // ------------------------- epilogue -------------------------
  if constexpr (EPI == 0) {
    if (swapped) {
      // Q block: m = channel j, col = token t. 4 regs = 4 consecutive d.
#pragma unroll
      for (int mt = 0; mt < 8; ++mt) {
        const int j0 = bn * 256 + wm * 128 + mt * 16 + lq * 4;
        const int h  = j0 >> 6, d0 = j0 & 63;
#pragma unroll
        for (int nt = 0; nt < 4; ++nt) {
          const int t = bm * 256 + wn * 64 + nt * 16 + lr;
          const int b = t >> 12, n = t & 4095;
          union { bf16 v[4]; ushort4 u; } pk;
#pragma unroll
          for (int r = 0; r < 4; ++r) {
            float v = acc[mt][nt][r];
            v = (v > 0.0f) ? (v + 1.0f) : __expf(v);
            pk.v[r] = __float2bfloat16(v);
          }
          *(ushort4*)(Qo + (((size_t)((b * 16 + h) * SEQ + n)) << 6) + d0) = pk.u;
        }
      }
    } else {
      // K/V block: m = token t, col = channel j. 4 regs = 4 consecutive n.
#pragma unroll
      for (int nt = 0; nt < 4; ++nt) {
        const int j   = bn * 256 + wn * 64 + nt * 16 + lr;
        const int sel = j >> 10;           // 1 = K, 2 = V
        const int h   = (j >> 6) & 15;
        const int d   = j & 63;
        bf16* dst = (sel == 1) ? Ko : Vo;
#pragma unroll
        for (int mt = 0; mt < 8; ++mt) {
          const int t0 = bm * 256 + wm * 128 + mt * 16 + lq * 4;
          const int b = t0 >> 12, n0 = t0 & 4095;
          union { bf16 v[4]; ushort4 u; } pk;
#pragma unroll
          for (int r = 0; r < 4; ++r) {
            float v = acc[mt][nt][r];
            if (sel == 1) v = (v > 0.0f) ? (v + 1.0f) : __expf(v);
            pk.v[r] = __float2bfloat16(v);
          }
          *(ushort4*)(dst + ((size_t)((b * 16 + h) * 64 + d)) * SEQ + n0) = pk.u;
        }
      }
    }
  } else {
    // proj: m = token t, col = channel. Coalesced scalar fp32 stores + bias.
#pragma unroll
    for (int mt = 0; mt < 8; ++mt) {
#pragma unroll
      for (int r = 0; r < 4; ++r) {
        const int t = bm * 256 + wm * 128 + mt * 16 + lq * 4 + r;
        float* op = Out + (size_t)t * CDIM + bn * 256 + wn * 64 + lr;
#pragma unroll
        for (int nt = 0; nt < 4; ++nt)
          op[nt * 16] = acc[mt][nt][r] + bias[bn * 256 + wn * 64 + nt * 16 + lr];
      }
    }
  }
}

// ---------------------------------------------------------------------------
// kv partials via MFMA.  Inputs K^T,V^T [bh][d][n] (n contiguous).
// Same T2 involution: LDS[row][c] = global[row][c ^ ((row&7)*8)].
// ---------------------------------------------------------------------------
__global__ __launch_bounds__(256) void kv_mfma(const bf16* __restrict__ KT,
                                               const bf16* __restrict__ VT,
                                               float* __restrict__ KVp,
                                               float* __restrict__ KSp) {
  __shared__ bf16 kt[64 * 64];
  __shared__ bf16 vt[64 * 64];
  const int tid = threadIdx.x;
  const int w = tid >> 6, lane = tid & 63;
  const int wm = w >> 1, wn = w & 1;
  const int lr = lane & 15, lq = lane >> 4;
  const int swz = (lr & 7) * 8;                            // read-side XOR
  const int csz = (((lane & 7) ^ (lane >> 3)) * 8);        // src-side pre-swizzle
  const int sp = blockIdx.x, bh = blockIdx.y;
  const bf16* kg0 = KT + (size_t)bh * 64 * SEQ + sp * 512;
  const bf16* vg0 = VT + (size_t)bh * 64 * SEQ + sp * 512;

  f32x4 acc[2][2] = {};
  f32x4 kacc0 = {}, kacc1 = {};
  short8 ones;
#pragma unroll
  for (int j = 0; j < 8; ++j) ((unsigned short*)&ones)[j] = 0x3F80;  // bf16 1.0

  for (int nc = 0; nc < 8; ++nc) {
    __syncthreads();
#pragma unroll
    for (int i = 0; i < 2; ++i) {
      const int row = w * 16 + i * 8 + (lane >> 3);
      async_load16(kg0 + (size_t)row * SEQ + nc * 64 + csz, kt + (w * 16 + i * 8) * 64);
      async_load16(vg0 + (size_t)row * SEQ + nc * 64 + csz, vt + (w * 16 + i * 8) * 64);
    }
    __syncthreads();

#pragma unroll
    for (int ks = 0; ks < 2; ++ks) {
      short8 a0 = *(const short8*)&kt[(wm * 32 +      lr) * 64 + ((ks * 32 + lq * 8) ^ swz)];
      short8 a1 = *(const short8*)&kt[(wm * 32 + 16 + lr) * 64 + ((ks * 32 + lq * 8) ^ swz)];
      short8 b0 = *(const short8*)&vt[(wn * 32 +      lr) * 64 + ((ks * 32 + lq * 8) ^ swz)];
      short8 b1 = *(const short8*)&vt[(wn * 32 + 16 + lr) * 64 + ((ks * 32 + lq * 8) ^ swz)];
      acc[0][0] = __builtin_amdgcn_mfma_f32_16x16x32_bf16(a0, b0, acc[0][0], 0, 0, 0);
      acc[0][1] = __builtin_amdgcn_mfma_f32_16x16x32_bf16(a0, b1, acc[0][1], 0, 0, 0);
      acc[1][0] = __builtin_amdgcn_mfma_f32_16x16x32_bf16(a1, b0, acc[1][0], 0, 0, 0);
      acc[1][1] = __builtin_amdgcn_mfma_f32_16x16x32_bf16(a1, b1, acc[1][1], 0, 0, 0);
      kacc0 = __builtin_amdgcn_mfma_f32_16x16x32_bf16(a0, ones, kacc0, 0, 0, 0);
      kacc1 = __builtin_amdgcn_mfma_f32_16x16x32_bf16(a1, ones, kacc1, 0, 0, 0);
    }
  }

  float* outp = KVp + ((size_t)(sp * 64 + bh)) * 4096;
#pragma unroll
  for (int mt = 0; mt < 2; ++mt)
#pragma unroll
    for (int nt = 0; nt < 2; ++nt) {
      const int e  = wn * 32 + nt * 16 + lr;
      const int d0 = wm * 32 + mt * 16 + lq * 4;
      *(float4*)&outp[e * 64 + d0] = *(float4*)&acc[mt][nt];
    }
  if (wn == 0 && lr == 0) {
    float* ksp = KSp + (size_t)(sp * 64 + bh) * 64 + wm * 32;
#pragma unroll
    for (int r = 0; r < 4; ++r) {
      ksp[lq * 4 + r]      = kacc0[r];
      ksp[16 + lq * 4 + r] = kacc1[r];
    }
  }
}

// ---------------------------------------------------------------------------
// reduce partials. grid 256 = (bh 64) x (quarter 4); each quarter does 4 of
// the 16 row-chunks (was one 64-block latency-bound kernel at 25% occupancy).
// ---------------------------------------------------------------------------
__global__ __launch_bounds__(256) void kv_reduce(const float* __restrict__ KVp,
                                                 const float* __restrict__ KSp,
                                                 bf16* __restrict__ KVT,
                                                 float* __restrict__ KS) {
  const int bh = blockIdx.x >> 2, q = blockIdx.x & 3, t = threadIdx.x;
#pragma unroll
  for (int i = 0; i < 4; ++i) {
    const int idx = (q * 4 + i) * 256 + t;
    float s = 0.0f;
#pragma unroll
    for (int sp = 0; sp < 8; ++sp) s += KVp[((size_t)(sp * 64 + bh)) * 4096 + idx];
    const bf16 hi = __float2bfloat16(s);
    const float lo = s - __bfloat162float(hi);
    const int e = idx >> 6, d = idx & 63;
    KVT[(size_t)bh * 8192 + e * 128 + d]      = hi;
    KVT[(size_t)bh * 8192 + e * 128 + 64 + d] = __float2bfloat16(lo);
  }
  if (q == 0 && t < 64) {
    float s = 0.0f;
#pragma unroll
    for (int sp = 0; sp < 8; ++sp) s += KSp[(sp * 64 + bh) * 64 + t];
    KS[bh * 64 + t] = s;
  }
}

// ---------------------------------------------------------------------------
// num = q @ kv. qs [128][64] and kvs [64][128] both carry the T2 involution
// LDS[row][c] = global[row][c ^ ((row&7)*8)] (chunk-granular, 8-elem chunks).
// ---------------------------------------------------------------------------
__global__ __launch_bounds__(256) void num_mfma(const bf16* __restrict__ Qb,
                                                const bf16* __restrict__ KVT,
                                                const float* __restrict__ KS,
                                                bf16* __restrict__ Attn) {
  __shared__ bf16 qs[128 * 64];
  __shared__ bf16 kvs[64 * 128];
  __shared__ bf16 Cs[128 * 72];
  __shared__ float ksl[64];
  __shared__ float dred[256];
  __shared__ float den[128];
  const int tid = threadIdx.x;
  const int w = tid >> 6, lane = tid & 63;
  const int wm = w >> 1, wn = w & 1;
  const int lr = lane & 15, lq = lane >> 4;
  const int swz = (lr & 7) * 8;
  const int bh = blockIdx.y, n00 = blockIdx.x * 128;
  const int b = bh >> 4, h = bh & 15;

  const bf16* qg  = Qb  + ((size_t)bh * SEQ + n00) * 64;
  const bf16* kvg = KVT + (size_t)bh * 8192;
  // qs: lane covers row base+(lane>>3), chunk lane&7 -> src chunk ^= row&7
  const int qcs = (((lane & 7) ^ (lane >> 3)) * 8);
#pragma unroll
  for (int i = 0; i < 4; ++i) {
    const int row = w * 32 + i * 8 + (lane >> 3);
    async_load16(qg + (size_t)row * 64 + qcs, qs + (w * 32 + i * 8) * 64);
  }
  // kvs: lane covers row base+(lane>>4), chunk lane&15 (128-elem rows)
#pragma unroll
  for (int i = 0; i < 4; ++i) {
    const int row = w * 16 + i * 4 + (lane >> 4);
    const int scol = (((lane & 15) * 8) ^ ((row & 7) * 8));
    async_load16(kvg + (size_t)row * 128 + scol, kvs + (w * 16 + i * 4) * 128);
  }
  if (tid < 64) ksl[tid] = KS[bh * 64 + tid];
  __syncthreads();

  {
    const int n = tid >> 1, half = tid & 1;
    const int nsw = (n & 7) * 8;
    float s = 0.0f;
#pragma unroll
    for (int v8 = 0; v8 < 4; ++v8) {
      short8 qq = *(const short8*)&qs[n * 64 + ((half * 32 + v8 * 8) ^ nsw)];
#pragma unroll
      for (int j = 0; j < 8; ++j)
        s += __bfloat162float(((const bf16*)&qq)[j]) * ksl[half * 32 + v8 * 8 + j];
    }
    dred[tid] = s;
  }

  short8 afr[4][2], bfr2[2][4];
#pragma unroll
  for (int mt = 0; mt < 4; ++mt)
#pragma unroll
    for (int kh = 0; kh < 2; ++kh)
      afr[mt][kh] = *(const short8*)&qs[(wm * 64 + mt * 16 + lr) * 64 + ((kh * 32 + lq * 8) ^ swz)];
#pragma unroll
  for (int nt = 0; nt < 2; ++nt)
#pragma unroll
    for (int ks = 0; ks < 4; ++ks)
      bfr2[nt][ks] = *(const short8*)&kvs[(wn * 32 + nt * 16 + lr) * 128 + ((ks * 32 + lq * 8) ^ swz)];

  f32x4 acc[4][2] = {};
#pragma unroll
  for (int ks = 0; ks < 4; ++ks)
#pragma unroll
    for (int mt = 0; mt < 4; ++mt)
#pragma unroll
      for (int nt = 0; nt < 2; ++nt)
        acc[mt][nt] = __builtin_amdgcn_mfma_f32_16x16x32_bf16(afr[mt][ks & 1], bfr2[nt][ks],
                                                              acc[mt][nt], 0, 0, 0);
  __syncthreads();
  if (tid < 128) den[tid] = dred[tid * 2] + dred[tid * 2 + 1] + 1e-8f;
  __syncthreads();

#pragma unroll
  for (int mt = 0; mt < 4; ++mt) {
#pragma unroll
    for (int r = 0; r < 4; ++r) {
      const int nl = wm * 64 + mt * 16 + lq * 4 + r;
      const float inv = 1.0f / den[nl];
#pragma unroll
      for (int nt = 0; nt < 2; ++nt) {
        const int e = wn * 32 + nt * 16 + lr;
        Cs[nl * 72 + e] = __float2bfloat16(acc[mt][nt][r] * inv);
      }
    }
  }
  __syncthreads();
#pragma unroll
  for (int it = 0; it < 4; ++it) {
    const int nl = it * 32 + (tid >> 3);
    const int ch = tid & 7;
    short8 val = *(const short8*)&Cs[nl * 72 + ch * 8];
    *(short8*)(Attn + ((size_t)(b * SEQ + n00 + nl)) * CDIM + h * 64 + ch * 8) = val;
  }
}

// ---------------------------------------------------------------------------
extern "C" void kernel_launch(void* const* d_in, const int* in_sizes, int n_in,
                              void* d_out, int out_size, void* d_ws, size_t ws_size,
                              hipStream_t stream) {
  const float* x      = (const float*)d_in[0];
  const float* w_qkv  = (const float*)d_in[1];
  const float* w_proj = (const float*)d_in[2];
  const float* b_proj = (const float*)d_in[3];
  float* out = (float*)d_out;
  char* ws = (char*)d_ws;

  bf16*  xb     = (bf16*)(ws + 0);
  bf16*  wqkvb  = (bf16*)(ws + 33554432);
  bf16*  wprojb = (bf16*)(ws + 39845888);
  bf16*  qb     = (bf16*)(ws + 41943040);
  bf16*  ktb    = (bf16*)(ws + 75497472);
  bf16*  vtb    = (bf16*)(ws + 109051904);
  float* kvp    = (float*)(ws + 0);
  float* ksp    = (float*)(ws + 8388608);
  bf16*  kvt    = (bf16*)(ws + 142606336);
  float* ksum   = (float*)(ws + 143654912);
  bf16*  attn   = (bf16*)(ws + 0);

  convert3_kernel<<<20480, 256, 0, stream>>>(x, w_qkv, w_proj, xb, wqkvb, wprojb);

  gemm256<0><<<dim3(12, 64), 512, 0, stream>>>(xb, wqkvb, nullptr, qb, ktb, vtb, nullptr, 1024);
  kv_mfma<<<dim3(8, 64), 256, 0, stream>>>(ktb, vtb, kvp, ksp);
  kv_reduce<<<256, 256, 0, stream>>>(kvp, ksp, kvt, ksum);
  num_mfma<<<dim3(32, 64), 256, 0, stream>>>(qb, kvt, ksum, attn);
  gemm256<1><<<dim3(4, 64), 512, 0, stream>>>(attn, wprojb, b_proj, nullptr, nullptr, nullptr, out, 1024);
}